// Round 27
// baseline (100.033 us; speedup 1.0000x reference)
//
#include <hip/hip_runtime.h>

// CTC loss forward, B=256 T=2000 L=100 C=36 (S=201, blank=35).
// Round-27 = R25 (best verified: 96.6us, absmax 0; FMA retest was null ->
// reverted to R25 add-form bodies) + two arithmetic-certain cuts:
//  1) BALANCED MEET at t=1008 (was 1100): alpha 1024 bodies (32 iters),
//     beta 992 bodies (31 iters) -- critical path 1120 -> 1024 (-8.6%).
//  2) RENORM EVERY 64 BODIES (was 32): f64 drift/64 bodies ~ e^275 ~ 2^397,
//     far inside 2^1023 even atop the ~300-nat state spread; halves the
//     serial 6-DPP renorm cost.
// Everything else verbatim R25: 4 waves (alpha fwd / beta bwd / 2x S_Z),
// gload_lds rings, WAITV(16)+SB0 half-batches, hoisted uniform branches
// (hot 16-body blocks / cold guarded loops), DPP neighbor exchange,
// meet-product combine in f64.

#define BB    256
#define TT    2000
#define LLAB  100
#define CC    36
#define BLANK 35
#define MEET  1008
#define LN2   0.6931471805599453

typedef __attribute__((address_space(1))) const unsigned int* as1_u32p;
typedef __attribute__((address_space(3))) unsigned int* as3_u32p;

__device__ __forceinline__ void async_row_load(const float* g, float* lds) {
  __builtin_amdgcn_global_load_lds((as1_u32p)(const void*)g,
                                   (as3_u32p)(void*)lds, 4, 0, 0);
}
#define WAITV(n) asm volatile("s_waitcnt vmcnt(" #n ")")
#define SB0 __builtin_amdgcn_sched_barrier(0)

static __device__ __forceinline__ int imax(int a, int b) { return a > b ? a : b; }
static __device__ __forceinline__ int hi32(double x) {
  return (int)(__double_as_longlong(x) >> 32);
}
// lane i <- lane i-1 (lane 0 gets 0): DPP wave_shr:1   [HW-verified]
static __device__ __forceinline__ double dpp_up1(double x) {
  long long v = __double_as_longlong(x);
  int lo = (int)(unsigned int)(v & 0xFFFFFFFFLL);
  int hi = (int)(v >> 32);
  int slo = __builtin_amdgcn_update_dpp(0, lo, 0x138, 0xF, 0xF, true);
  int shi = __builtin_amdgcn_update_dpp(0, hi, 0x138, 0xF, 0xF, true);
  return __longlong_as_double(((long long)shi << 32) | (unsigned int)slo);
}
// lane i <- lane i+1 (lane 63 gets 0): DPP wave_shl:1   [HW-verified]
static __device__ __forceinline__ double dpp_dn1(double x) {
  long long v = __double_as_longlong(x);
  int lo = (int)(unsigned int)(v & 0xFFFFFFFFLL);
  int hi = (int)(v >> 32);
  int slo = __builtin_amdgcn_update_dpp(0, lo, 0x130, 0xF, 0xF, true);
  int shi = __builtin_amdgcn_update_dpp(0, hi, 0x130, 0xF, 0xF, true);
  return __longlong_as_double(((long long)shi << 32) | (unsigned int)slo);
}
// wave-wide int max via DPP, broadcast from lane 63.
static __device__ __forceinline__ int wave_imax(int x) {
  x = imax(x, __builtin_amdgcn_update_dpp(x, x, 0x111, 0xF, 0xF, false));
  x = imax(x, __builtin_amdgcn_update_dpp(x, x, 0x112, 0xF, 0xF, false));
  x = imax(x, __builtin_amdgcn_update_dpp(x, x, 0x114, 0xF, 0xF, false));
  x = imax(x, __builtin_amdgcn_update_dpp(x, x, 0x118, 0xF, 0xF, false));
  x = imax(x, __builtin_amdgcn_update_dpp(x, x, 0x142, 0xA, 0xF, false));
  x = imax(x, __builtin_amdgcn_update_dpp(x, x, 0x143, 0xC, 0xF, false));
  return __builtin_amdgcn_readlane(x, 63);
}

__global__ __launch_bounds__(256, 1) void ctc_fused(
    const float* __restrict__ logits,
    const int*   __restrict__ input_labels,
    const int*   __restrict__ input_len,
    const int*   __restrict__ label_len,
    float*       __restrict__ out)
{
  __shared__ float  ringF[64][CC];     // alpha rows (9216 B)
  __shared__ float  ringB[64][CC];     // beta rows (9216 B)
  __shared__ double bsh[64][4];        // beta_1008 publish
  __shared__ float  szsh[2];           // S_Z halves
  __shared__ int    eaccsh;            // beta's Eacc
  const int b    = blockIdx.x;
  const int tid  = threadIdx.x;
  const int wave = tid >> 6;
  const int lane = tid & 63;
  const float* lg = logits + (size_t)b * TT * CC;
  const int ilen = input_len[b];
  const int llen = label_len[b];

  double fa0 = 0.0, fa1 = 0.0, fa2 = 0.0, fa3 = 0.0;  // wave0 final alpha
  int EaccA = 0;

  if (wave >= 2) {
    // ================= WAVES 2,3: S_Z halves (parallel w/ chains) =========
    float sz = 0.f;
    const int base = (wave == 2) ? 0 : 1000;
    for (int t = base + lane; t < base + 1000; t += 64) {
      const float4* r4 = (const float4*)(lg + (size_t)t * CC);
      float4 q[9];
#pragma unroll
      for (int i = 0; i < 9; ++i) q[i] = r4[i];
      float m = q[0].x;
#pragma unroll
      for (int i = 0; i < 9; ++i) {
        m = fmaxf(m, q[i].x); m = fmaxf(m, q[i].y);
        m = fmaxf(m, q[i].z); m = fmaxf(m, q[i].w);
      }
      float s = 0.f;
#pragma unroll
      for (int i = 0; i < 9; ++i) {
        s += __expf(q[i].x - m) + __expf(q[i].y - m)
           + __expf(q[i].z - m) + __expf(q[i].w - m);
      }
      float z = m + __logf(s);
      if (t == 0 || t < ilen) sz += z;
    }
#pragma unroll
    for (int o = 32; o; o >>= 1) sz += __shfl_xor(sz, o, 64);
    if (lane == 0) szsh[wave - 2] = sz;
  } else {
    // ---------------- per-lane label state (waves 0,1) --------------------
    const int* lb = input_labels + b * LLAB;
    const int i0 = 2 * lane, i1 = 2 * lane + 1, im = 2 * lane - 1, ix = 2 * lane + 2;
    const int c1  = (i0 < LLAB) ? lb[i0] : 0;
    const int c3  = (i1 < LLAB) ? lb[i1] : 0;
    const int cm  = (im >= 0 && im < LLAB) ? lb[im] : 0;
    const int cnx = (ix < LLAB) ? lb[ix] : 0;
    const int cb = BLANK;

    if (wave == 0) {
      // =============== WAVE 0: alpha forward, bodies t=1..1024 ============
      const double sk1d = ((lane >= 1) && (c1 != BLANK) && (c1 != cm)) ? 1.0 : 0.0;
      const double sk3d = (c3 != c1) ? 1.0 : 0.0;
      double a0 = 0.0, a1 = 0.0, a2 = 0.0, a3 = 0.0;
      {
        float eb = lg[BLANK], e1 = lg[c1];
        if (lane == 0) { a0 = (double)__expf(eb); a1 = (double)__expf(e1); }
      }
      asm volatile("s_waitcnt vmcnt(0) lgkmcnt(0)" ::: "memory");
      if (lane < CC) {
#pragma unroll
        for (int r = 1; r <= 32; ++r)
          async_row_load(lg + (size_t)r * CC + lane, &ringF[r & 63][0]);
      }
      float eAb[16], eA1[16], eA3[16], eBb[16], eB1[16], eB3[16];
      WAITV(16); SB0;
#pragma unroll
      for (int j = 0; j < 16; ++j) {          // exp batch 0 (rows 1..16)
        const float* rp = &ringF[(1 + j) & 63][0];
        eAb[j] = __expf(rp[cb]); eA1[j] = __expf(rp[c1]); eA3[j] = __expf(rp[c3]);
      }
      SB0;
      double n3 = 0.0, n3k = 0.0;
      const int aEnd = (ilen < (MEET + 1)) ? ilen : (MEET + 1);

      // unconditional body (hot path -- no scalar branch)
#define ABODY_U(Eb, E1, E3)                                                \
      {                                                                    \
        double p0 = (double)(Eb), p1 = (double)(E1), p3 = (double)(E3);    \
        double u0 = (a0 + n3) * p0;                                        \
        double u1 = (a1 + a0 + n3k) * p1;                                  \
        double u2 = (a2 + a1) * p0;                                        \
        double u3 = (a3 + a2 + a1 * sk3d) * p3;                            \
        a0 = u0; a1 = u1; a2 = u2; a3 = u3;                                \
        n3 = dpp_up1(a3); n3k = n3 * sk1d;                                 \
      }
      // guarded body (cold path, rolled)
#define ABODY_G(T, Eb, E1, E3)                                             \
      {                                                                    \
        if ((T) < aEnd) {                                                  \
          double p0 = (double)(Eb), p1 = (double)(E1), p3 = (double)(E3);  \
          double u0 = (a0 + n3) * p0;                                      \
          double u1 = (a1 + a0 + n3k) * p1;                                \
          double u2 = (a2 + a1) * p0;                                      \
          double u3 = (a3 + a2 + a1 * sk3d) * p3;                          \
          a0 = u0; a1 = u1; a2 = u2; a3 = u3;                              \
        }                                                                  \
        n3 = dpp_up1(a3); n3k = n3 * sk1d;                                 \
      }

      // 32 iters x 2 half-batches x 16 bodies: t = 1..1024; renorm / 2 iters
#pragma unroll 1
      for (int m = 0; m < 32; ++m) {
        const int T0 = 1 + 32 * m;
        if (lane < CC) {                       // gload rows T0+32..T0+47
#pragma unroll
          for (int i = 0; i < 16; ++i)
            async_row_load(lg + (size_t)(T0 + 32 + i) * CC + lane,
                           &ringF[(T0 + 32 + i) & 63][0]);
        }
        WAITV(16); SB0;
#pragma unroll
        for (int j = 0; j < 16; ++j) {         // exp rows T0+16..T0+31
          const float* rp = &ringF[(T0 + 16 + j) & 63][0];
          eBb[j] = __expf(rp[cb]); eB1[j] = __expf(rp[c1]); eB3[j] = __expf(rp[c3]);
        }
        SB0;
        if (T0 + 16 <= aEnd) {                 // bodies T0..T0+15 all update
#pragma unroll
          for (int j = 0; j < 16; ++j) { ABODY_U(eAb[j], eA1[j], eA3[j]) }
        } else {
#pragma unroll 1
          for (int j = 0; j < 16; ++j) { ABODY_G(T0 + j, eAb[j], eA1[j], eA3[j]) }
        }
        if (lane < CC) {                       // gload rows T0+48..T0+63
#pragma unroll
          for (int i = 0; i < 16; ++i)
            async_row_load(lg + (size_t)(T0 + 48 + i) * CC + lane,
                           &ringF[(T0 + 48 + i) & 63][0]);
        }
        WAITV(16); SB0;
#pragma unroll
        for (int j = 0; j < 16; ++j) {         // exp rows T0+32..T0+47
          const float* rp = &ringF[(T0 + 32 + j) & 63][0];
          eAb[j] = __expf(rp[cb]); eA1[j] = __expf(rp[c1]); eA3[j] = __expf(rp[c3]);
        }
        SB0;
        if (T0 + 32 <= aEnd) {                 // bodies T0+16..T0+31 all update
#pragma unroll
          for (int j = 0; j < 16; ++j) { ABODY_U(eBb[j], eB1[j], eB3[j]) }
        } else {
#pragma unroll 1
          for (int j = 0; j < 16; ++j) { ABODY_G(T0 + 16 + j, eBb[j], eB1[j], eB3[j]) }
        }
        if (m & 1) {                           // renorm every 64 bodies
          int h = imax(imax(hi32(a0), hi32(a1)), imax(hi32(a2), hi32(a3)));
          int e = wave_imax(h) >> 20;
          EaccA += e - 1023;
          double s = __longlong_as_double((long long)(2046 - e) << 52);
          a0 *= s; a1 *= s; a2 *= s; a3 *= s; n3 *= s; n3k *= s;
        }
      }
#undef ABODY_U
#undef ABODY_G
      asm volatile("s_waitcnt vmcnt(0)");      // drain leftover gloads
      fa0 = a0; fa1 = a1; fa2 = a2; fa3 = a3;
    } else {
      // =============== WAVE 1: beta backward, bodies r=1999..1008 =========
      const double skB1d = (c3 != c1) ? 1.0 : 0.0;
      const double skB3d = (cnx != c3) ? 1.0 : 0.0;
      const int sb4 = 4 * lane;
      const int end = 2 * llen;
      const int ep  = (end > 0) ? (end - 1) : 0;
      double b0 = (double)((sb4 + 0 == end) + (sb4 + 0 == ep));
      double b1 = (double)((sb4 + 1 == end) + (sb4 + 1 == ep));
      double b2 = (double)((sb4 + 2 == end) + (sb4 + 2 == ep));
      double b3 = (double)((sb4 + 3 == end) + (sb4 + 3 == ep));
      asm volatile("s_waitcnt vmcnt(0) lgkmcnt(0)" ::: "memory");
      if (lane < CC) {
#pragma unroll
        for (int r = 0; r < 32; ++r)
          async_row_load(lg + (size_t)(1999 - r) * CC + lane,
                         &ringB[(1999 - r) & 63][0]);
      }
      float eAb[16], eA1[16], eA3[16], eAx[16];
      float eBb[16], eB1[16], eB3[16], eBx[16];
      WAITV(16); SB0;
#pragma unroll
      for (int j = 0; j < 16; ++j) {          // exp batch 0 (rows 1999..1984)
        const float* rp = &ringB[(1999 - j) & 63][0];
        eAb[j] = __expf(rp[cb]);  eA1[j] = __expf(rp[c1]);
        eA3[j] = __expf(rp[c3]);  eAx[j] = __expf(rp[cnx]);
      }
      SB0;
      double nb0 = dpp_dn1(b0), nb1 = dpp_dn1(b1);
      int EaccB = 0;

#define BBODY_U(Eb, E1, E3, Ex)                                            \
      {                                                                    \
        double p0 = (double)(Eb), p1 = (double)(E1);                       \
        double p3 = (double)(E3), px = (double)(Ex);                       \
        double tB1 = p1 * b1, tB2 = p0 * b2, tB3 = p3 * b3;                \
        double v0 = p0 * b0 + tB1;                                         \
        double v1 = tB1 + tB2 + tB3 * skB1d;                               \
        double v2 = tB2 + tB3;                                             \
        double v3 = tB3 + p0 * nb0 + (px * nb1) * skB3d;                   \
        b0 = v0; b1 = v1; b2 = v2; b3 = v3;                                \
        nb0 = dpp_dn1(b0); nb1 = dpp_dn1(b1);                              \
      }
#define BBODY_G(R, Eb, E1, E3, Ex)                                         \
      {                                                                    \
        if ((R) > MEET && (R) < ilen) {                                    \
          double p0 = (double)(Eb), p1 = (double)(E1);                     \
          double p3 = (double)(E3), px = (double)(Ex);                     \
          double tB1 = p1 * b1, tB2 = p0 * b2, tB3 = p3 * b3;              \
          double v0 = p0 * b0 + tB1;                                       \
          double v1 = tB1 + tB2 + tB3 * skB1d;                             \
          double v2 = tB2 + tB3;                                           \
          double v3 = tB3 + p0 * nb0 + (px * nb1) * skB3d;                 \
          b0 = v0; b1 = v1; b2 = v2; b3 = v3;                              \
        }                                                                  \
        nb0 = dpp_dn1(b0); nb1 = dpp_dn1(b1);                              \
      }

      // 31 iters x 2 half-batches x 16 bodies: r = 1999..1008; renorm / 2
#pragma unroll 1
      for (int m = 0; m < 31; ++m) {
        const int R0 = 1999 - 32 * m;
        if (lane < CC) {                       // gload rows R0-32..R0-47
#pragma unroll
          for (int i = 0; i < 16; ++i)
            async_row_load(lg + (size_t)(R0 - 32 - i) * CC + lane,
                           &ringB[(R0 - 32 - i) & 63][0]);
        }
        WAITV(16); SB0;
#pragma unroll
        for (int j = 0; j < 16; ++j) {         // exp rows R0-16..R0-31
          const float* rp = &ringB[(R0 - 16 - j) & 63][0];
          eBb[j] = __expf(rp[cb]);  eB1[j] = __expf(rp[c1]);
          eB3[j] = __expf(rp[c3]);  eBx[j] = __expf(rp[cnx]);
        }
        SB0;
        if ((R0 - 15 > MEET) && (R0 < ilen)) { // bodies R0..R0-15 all update
#pragma unroll
          for (int j = 0; j < 16; ++j) { BBODY_U(eAb[j], eA1[j], eA3[j], eAx[j]) }
        } else {
#pragma unroll 1
          for (int j = 0; j < 16; ++j) { BBODY_G(R0 - j, eAb[j], eA1[j], eA3[j], eAx[j]) }
        }
        if (lane < CC) {                       // gload rows R0-48..R0-63
#pragma unroll
          for (int i = 0; i < 16; ++i)
            async_row_load(lg + (size_t)(R0 - 48 - i) * CC + lane,
                           &ringB[(R0 - 48 - i) & 63][0]);
        }
        WAITV(16); SB0;
#pragma unroll
        for (int j = 0; j < 16; ++j) {         // exp rows R0-32..R0-47
          const float* rp = &ringB[(R0 - 32 - j) & 63][0];
          eAb[j] = __expf(rp[cb]);  eA1[j] = __expf(rp[c1]);
          eA3[j] = __expf(rp[c3]);  eAx[j] = __expf(rp[cnx]);
        }
        SB0;
        if ((R0 - 31 > MEET) && (R0 - 16 < ilen)) {   // bodies R0-16..R0-31
#pragma unroll
          for (int j = 0; j < 16; ++j) { BBODY_U(eBb[j], eB1[j], eB3[j], eBx[j]) }
        } else {
#pragma unroll 1
          for (int j = 0; j < 16; ++j) { BBODY_G(R0 - 16 - j, eBb[j], eB1[j], eB3[j], eBx[j]) }
        }
        if (m & 1) {                           // renorm every 64 bodies
          int h = imax(imax(hi32(b0), hi32(b1)), imax(hi32(b2), hi32(b3)));
          int e = wave_imax(h) >> 20;
          EaccB += e - 1023;
          double s = __longlong_as_double((long long)(2046 - e) << 52);
          b0 *= s; b1 *= s; b2 *= s; b3 *= s; nb0 *= s; nb1 *= s;
        }
      }
#undef BBODY_U
#undef BBODY_G
      asm volatile("s_waitcnt vmcnt(0)");      // drain leftover gloads
      bsh[lane][0] = b0; bsh[lane][1] = b1;
      bsh[lane][2] = b2; bsh[lane][3] = b3;
      if (lane == 0) eaccsh = EaccB;
    }
  }

  __syncthreads();                             // publish beta, S_Z halves

  if (wave == 0) {
    double contrib = fa0 * bsh[lane][0] + fa1 * bsh[lane][1]
                   + fa2 * bsh[lane][2] + fa3 * bsh[lane][3];
#pragma unroll
    for (int o = 32; o; o >>= 1) contrib += __shfl_xor(contrib, o, 64);
    if (lane == 0) {
      long long u = __double_as_longlong(contrib);
      int e = (int)((u >> 52) & 0x7FF) - 1023;
      double mant = __longlong_as_double(
          (u & 0xFFFFFFFFFFFFFULL) | 0x3FF0000000000000ULL);
      double lc = (double)e * LN2 + (double)__logf((float)mant);
      double loss = -(lc + (double)(EaccA + eaccsh) * LN2
                      - (double)(szsh[0] + szsh[1]));
      out[b] = (float)loss;
    }
  }
}

extern "C" void kernel_launch(void* const* d_in, const int* in_sizes, int n_in,
                              void* d_out, int out_size, void* d_ws, size_t ws_size,
                              hipStream_t stream) {
  const float* logits = (const float*)d_in[0];
  const int* labels   = (const int*)d_in[1];
  const int* ilen     = (const int*)d_in[2];
  const int* llen     = (const int*)d_in[3];
  float* out          = (float*)d_out;
  (void)in_sizes; (void)n_in; (void)out_size; (void)d_ws; (void)ws_size;
  hipLaunchKernelGGL(ctc_fused, dim3(BB), dim3(256), 0, stream,
                     logits, labels, ilen, llen, out);
}

// Round 28
// 96.362 us; speedup vs baseline: 1.0381x; 1.0381x over previous
//
#include <hip/hip_runtime.h>

// CTC loss forward, B=256 T=2000 L=100 C=36 (S=201, blank=35).
// FINAL = Round-25 verbatim (best verified: 96.6us, absmax 0.0).
// R27's "balanced meet" regressed: beta bodies cost ~1.25x alpha bodies
// (4 exps vs 3, ~12 f64 vs ~10, 2 DPP vs 1), so the cost-weighted optimal
// meet is t* ~ 2000*1.25/2.25 ~ 1111 -- R25's MEET=1100 was already optimal.
// Structure: 256 blocks x 4 waves --
//   w0: alpha forward (f64, 4 states/lane, bodies t=1..1120, meet t=1100)
//   w1: beta backward (bodies r=1999..1072)
//   w2/w3: S_Z halves (sum_t logsumexp) in parallel with the chains
// Techniques that survived ablation: linear-domain f64 recursion with exact
// pow2 renorm (446->231us), fwd/bwd meet-product split across waves
// (231->121us), gload_lds rings + batch-granular WAITV(16)+SB0 staging,
// HOISTED uniform branches (hot 16-body branch-free blocks / cold rolled
// guarded loops; 122->96.6us -- per-body s_cbranch was ~50cy of fetch
// redirect), DPP neighbor exchange, f64 meet-product combine.
// Nulls (falsified): deeper prefetch, reg-ring staging, FMA-form bodies,
// TLP packing, f32 chains (5 numerics failures), meet rebalancing.

#define BB    256
#define TT    2000
#define LLAB  100
#define CC    36
#define BLANK 35
#define MEET  1100
#define LN2   0.6931471805599453

typedef __attribute__((address_space(1))) const unsigned int* as1_u32p;
typedef __attribute__((address_space(3))) unsigned int* as3_u32p;

__device__ __forceinline__ void async_row_load(const float* g, float* lds) {
  __builtin_amdgcn_global_load_lds((as1_u32p)(const void*)g,
                                   (as3_u32p)(void*)lds, 4, 0, 0);
}
#define WAITV(n) asm volatile("s_waitcnt vmcnt(" #n ")")
#define SB0 __builtin_amdgcn_sched_barrier(0)

static __device__ __forceinline__ int imax(int a, int b) { return a > b ? a : b; }
static __device__ __forceinline__ int hi32(double x) {
  return (int)(__double_as_longlong(x) >> 32);
}
// lane i <- lane i-1 (lane 0 gets 0): DPP wave_shr:1   [HW-verified]
static __device__ __forceinline__ double dpp_up1(double x) {
  long long v = __double_as_longlong(x);
  int lo = (int)(unsigned int)(v & 0xFFFFFFFFLL);
  int hi = (int)(v >> 32);
  int slo = __builtin_amdgcn_update_dpp(0, lo, 0x138, 0xF, 0xF, true);
  int shi = __builtin_amdgcn_update_dpp(0, hi, 0x138, 0xF, 0xF, true);
  return __longlong_as_double(((long long)shi << 32) | (unsigned int)slo);
}
// lane i <- lane i+1 (lane 63 gets 0): DPP wave_shl:1   [HW-verified]
static __device__ __forceinline__ double dpp_dn1(double x) {
  long long v = __double_as_longlong(x);
  int lo = (int)(unsigned int)(v & 0xFFFFFFFFLL);
  int hi = (int)(v >> 32);
  int slo = __builtin_amdgcn_update_dpp(0, lo, 0x130, 0xF, 0xF, true);
  int shi = __builtin_amdgcn_update_dpp(0, hi, 0x130, 0xF, 0xF, true);
  return __longlong_as_double(((long long)shi << 32) | (unsigned int)slo);
}
// wave-wide int max via DPP, broadcast from lane 63.
static __device__ __forceinline__ int wave_imax(int x) {
  x = imax(x, __builtin_amdgcn_update_dpp(x, x, 0x111, 0xF, 0xF, false));
  x = imax(x, __builtin_amdgcn_update_dpp(x, x, 0x112, 0xF, 0xF, false));
  x = imax(x, __builtin_amdgcn_update_dpp(x, x, 0x114, 0xF, 0xF, false));
  x = imax(x, __builtin_amdgcn_update_dpp(x, x, 0x118, 0xF, 0xF, false));
  x = imax(x, __builtin_amdgcn_update_dpp(x, x, 0x142, 0xA, 0xF, false));
  x = imax(x, __builtin_amdgcn_update_dpp(x, x, 0x143, 0xC, 0xF, false));
  return __builtin_amdgcn_readlane(x, 63);
}

__global__ __launch_bounds__(256, 1) void ctc_fused(
    const float* __restrict__ logits,
    const int*   __restrict__ input_labels,
    const int*   __restrict__ input_len,
    const int*   __restrict__ label_len,
    float*       __restrict__ out)
{
  __shared__ float  ringF[64][CC];     // alpha rows (9216 B)
  __shared__ float  ringB[64][CC];     // beta rows (9216 B)
  __shared__ double bsh[64][4];        // beta_1100 publish
  __shared__ float  szsh[2];           // S_Z halves
  __shared__ int    eaccsh;            // beta's Eacc
  const int b    = blockIdx.x;
  const int tid  = threadIdx.x;
  const int wave = tid >> 6;
  const int lane = tid & 63;
  const float* lg = logits + (size_t)b * TT * CC;
  const int ilen = input_len[b];
  const int llen = label_len[b];

  double fa0 = 0.0, fa1 = 0.0, fa2 = 0.0, fa3 = 0.0;  // wave0 final alpha
  int EaccA = 0;

  if (wave >= 2) {
    // ================= WAVES 2,3: S_Z halves (parallel w/ chains) =========
    float sz = 0.f;
    const int base = (wave == 2) ? 0 : 1000;
    for (int t = base + lane; t < base + 1000; t += 64) {
      const float4* r4 = (const float4*)(lg + (size_t)t * CC);
      float4 q[9];
#pragma unroll
      for (int i = 0; i < 9; ++i) q[i] = r4[i];
      float m = q[0].x;
#pragma unroll
      for (int i = 0; i < 9; ++i) {
        m = fmaxf(m, q[i].x); m = fmaxf(m, q[i].y);
        m = fmaxf(m, q[i].z); m = fmaxf(m, q[i].w);
      }
      float s = 0.f;
#pragma unroll
      for (int i = 0; i < 9; ++i) {
        s += __expf(q[i].x - m) + __expf(q[i].y - m)
           + __expf(q[i].z - m) + __expf(q[i].w - m);
      }
      float z = m + __logf(s);
      if (t == 0 || t < ilen) sz += z;
    }
#pragma unroll
    for (int o = 32; o; o >>= 1) sz += __shfl_xor(sz, o, 64);
    if (lane == 0) szsh[wave - 2] = sz;
  } else {
    // ---------------- per-lane label state (waves 0,1) --------------------
    const int* lb = input_labels + b * LLAB;
    const int i0 = 2 * lane, i1 = 2 * lane + 1, im = 2 * lane - 1, ix = 2 * lane + 2;
    const int c1  = (i0 < LLAB) ? lb[i0] : 0;
    const int c3  = (i1 < LLAB) ? lb[i1] : 0;
    const int cm  = (im >= 0 && im < LLAB) ? lb[im] : 0;
    const int cnx = (ix < LLAB) ? lb[ix] : 0;
    const int cb = BLANK;

    if (wave == 0) {
      // =============== WAVE 0: alpha forward, bodies t=1..1120 ============
      const double sk1d = ((lane >= 1) && (c1 != BLANK) && (c1 != cm)) ? 1.0 : 0.0;
      const double sk3d = (c3 != c1) ? 1.0 : 0.0;
      double a0 = 0.0, a1 = 0.0, a2 = 0.0, a3 = 0.0;
      {
        float eb = lg[BLANK], e1 = lg[c1];
        if (lane == 0) { a0 = (double)__expf(eb); a1 = (double)__expf(e1); }
      }
      asm volatile("s_waitcnt vmcnt(0) lgkmcnt(0)" ::: "memory");
      if (lane < CC) {
#pragma unroll
        for (int r = 1; r <= 32; ++r)
          async_row_load(lg + (size_t)r * CC + lane, &ringF[r & 63][0]);
      }
      float eAb[16], eA1[16], eA3[16], eBb[16], eB1[16], eB3[16];
      WAITV(16); SB0;
#pragma unroll
      for (int j = 0; j < 16; ++j) {          // exp batch 0 (rows 1..16)
        const float* rp = &ringF[(1 + j) & 63][0];
        eAb[j] = __expf(rp[cb]); eA1[j] = __expf(rp[c1]); eA3[j] = __expf(rp[c3]);
      }
      SB0;
      double n3 = 0.0, n3k = 0.0;
      const int aEnd = (ilen < (MEET + 1)) ? ilen : (MEET + 1);

      // unconditional body (hot path -- no scalar branch)
#define ABODY_U(Eb, E1, E3)                                                \
      {                                                                    \
        double p0 = (double)(Eb), p1 = (double)(E1), p3 = (double)(E3);    \
        double u0 = (a0 + n3) * p0;                                        \
        double u1 = (a1 + a0 + n3k) * p1;                                  \
        double u2 = (a2 + a1) * p0;                                        \
        double u3 = (a3 + a2 + a1 * sk3d) * p3;                            \
        a0 = u0; a1 = u1; a2 = u2; a3 = u3;                                \
        n3 = dpp_up1(a3); n3k = n3 * sk1d;                                 \
      }
      // guarded body (cold path, rolled)
#define ABODY_G(T, Eb, E1, E3)                                             \
      {                                                                    \
        if ((T) < aEnd) {                                                  \
          double p0 = (double)(Eb), p1 = (double)(E1), p3 = (double)(E3);  \
          double u0 = (a0 + n3) * p0;                                      \
          double u1 = (a1 + a0 + n3k) * p1;                                \
          double u2 = (a2 + a1) * p0;                                      \
          double u3 = (a3 + a2 + a1 * sk3d) * p3;                          \
          a0 = u0; a1 = u1; a2 = u2; a3 = u3;                              \
        }                                                                  \
        n3 = dpp_up1(a3); n3k = n3 * sk1d;                                 \
      }

      // 35 iters x 2 half-batches x 16 bodies: t = 1..1120
#pragma unroll 1
      for (int m = 0; m < 35; ++m) {
        const int T0 = 1 + 32 * m;
        if (lane < CC) {                       // gload rows T0+32..T0+47
#pragma unroll
          for (int i = 0; i < 16; ++i)
            async_row_load(lg + (size_t)(T0 + 32 + i) * CC + lane,
                           &ringF[(T0 + 32 + i) & 63][0]);
        }
        WAITV(16); SB0;
#pragma unroll
        for (int j = 0; j < 16; ++j) {         // exp rows T0+16..T0+31
          const float* rp = &ringF[(T0 + 16 + j) & 63][0];
          eBb[j] = __expf(rp[cb]); eB1[j] = __expf(rp[c1]); eB3[j] = __expf(rp[c3]);
        }
        SB0;
        if (T0 + 16 <= aEnd) {                 // bodies T0..T0+15 all update
#pragma unroll
          for (int j = 0; j < 16; ++j) { ABODY_U(eAb[j], eA1[j], eA3[j]) }
        } else {
#pragma unroll 1
          for (int j = 0; j < 16; ++j) { ABODY_G(T0 + j, eAb[j], eA1[j], eA3[j]) }
        }
        if (lane < CC) {                       // gload rows T0+48..T0+63
#pragma unroll
          for (int i = 0; i < 16; ++i)
            async_row_load(lg + (size_t)(T0 + 48 + i) * CC + lane,
                           &ringF[(T0 + 48 + i) & 63][0]);
        }
        WAITV(16); SB0;
#pragma unroll
        for (int j = 0; j < 16; ++j) {         // exp rows T0+32..T0+47
          const float* rp = &ringF[(T0 + 32 + j) & 63][0];
          eAb[j] = __expf(rp[cb]); eA1[j] = __expf(rp[c1]); eA3[j] = __expf(rp[c3]);
        }
        SB0;
        if (T0 + 32 <= aEnd) {                 // bodies T0+16..T0+31 all update
#pragma unroll
          for (int j = 0; j < 16; ++j) { ABODY_U(eBb[j], eB1[j], eB3[j]) }
        } else {
#pragma unroll 1
          for (int j = 0; j < 16; ++j) { ABODY_G(T0 + 16 + j, eBb[j], eB1[j], eB3[j]) }
        }
        {                                      // renorm every 32 bodies
          int h = imax(imax(hi32(a0), hi32(a1)), imax(hi32(a2), hi32(a3)));
          int e = wave_imax(h) >> 20;
          EaccA += e - 1023;
          double s = __longlong_as_double((long long)(2046 - e) << 52);
          a0 *= s; a1 *= s; a2 *= s; a3 *= s; n3 *= s; n3k *= s;
        }
      }
#undef ABODY_U
#undef ABODY_G
      asm volatile("s_waitcnt vmcnt(0)");      // drain leftover gloads
      fa0 = a0; fa1 = a1; fa2 = a2; fa3 = a3;
    } else {
      // =============== WAVE 1: beta backward, bodies r=1999..1072 =========
      const double skB1d = (c3 != c1) ? 1.0 : 0.0;
      const double skB3d = (cnx != c3) ? 1.0 : 0.0;
      const int sb4 = 4 * lane;
      const int end = 2 * llen;
      const int ep  = (end > 0) ? (end - 1) : 0;
      double b0 = (double)((sb4 + 0 == end) + (sb4 + 0 == ep));
      double b1 = (double)((sb4 + 1 == end) + (sb4 + 1 == ep));
      double b2 = (double)((sb4 + 2 == end) + (sb4 + 2 == ep));
      double b3 = (double)((sb4 + 3 == end) + (sb4 + 3 == ep));
      asm volatile("s_waitcnt vmcnt(0) lgkmcnt(0)" ::: "memory");
      if (lane < CC) {
#pragma unroll
        for (int r = 0; r < 32; ++r)
          async_row_load(lg + (size_t)(1999 - r) * CC + lane,
                         &ringB[(1999 - r) & 63][0]);
      }
      float eAb[16], eA1[16], eA3[16], eAx[16];
      float eBb[16], eB1[16], eB3[16], eBx[16];
      WAITV(16); SB0;
#pragma unroll
      for (int j = 0; j < 16; ++j) {          // exp batch 0 (rows 1999..1984)
        const float* rp = &ringB[(1999 - j) & 63][0];
        eAb[j] = __expf(rp[cb]);  eA1[j] = __expf(rp[c1]);
        eA3[j] = __expf(rp[c3]);  eAx[j] = __expf(rp[cnx]);
      }
      SB0;
      double nb0 = dpp_dn1(b0), nb1 = dpp_dn1(b1);
      int EaccB = 0;

#define BBODY_U(Eb, E1, E3, Ex)                                            \
      {                                                                    \
        double p0 = (double)(Eb), p1 = (double)(E1);                       \
        double p3 = (double)(E3), px = (double)(Ex);                       \
        double tB1 = p1 * b1, tB2 = p0 * b2, tB3 = p3 * b3;                \
        double v0 = p0 * b0 + tB1;                                         \
        double v1 = tB1 + tB2 + tB3 * skB1d;                               \
        double v2 = tB2 + tB3;                                             \
        double v3 = tB3 + p0 * nb0 + (px * nb1) * skB3d;                   \
        b0 = v0; b1 = v1; b2 = v2; b3 = v3;                                \
        nb0 = dpp_dn1(b0); nb1 = dpp_dn1(b1);                              \
      }
#define BBODY_G(R, Eb, E1, E3, Ex)                                         \
      {                                                                    \
        if ((R) > MEET && (R) < ilen) {                                    \
          double p0 = (double)(Eb), p1 = (double)(E1);                     \
          double p3 = (double)(E3), px = (double)(Ex);                     \
          double tB1 = p1 * b1, tB2 = p0 * b2, tB3 = p3 * b3;              \
          double v0 = p0 * b0 + tB1;                                       \
          double v1 = tB1 + tB2 + tB3 * skB1d;                             \
          double v2 = tB2 + tB3;                                           \
          double v3 = tB3 + p0 * nb0 + (px * nb1) * skB3d;                 \
          b0 = v0; b1 = v1; b2 = v2; b3 = v3;                              \
        }                                                                  \
        nb0 = dpp_dn1(b0); nb1 = dpp_dn1(b1);                              \
      }

      // 29 iters x 2 half-batches x 16 bodies: r = 1999..1072
#pragma unroll 1
      for (int m = 0; m < 29; ++m) {
        const int R0 = 1999 - 32 * m;
        if (lane < CC) {                       // gload rows R0-32..R0-47
#pragma unroll
          for (int i = 0; i < 16; ++i)
            async_row_load(lg + (size_t)(R0 - 32 - i) * CC + lane,
                           &ringB[(R0 - 32 - i) & 63][0]);
        }
        WAITV(16); SB0;
#pragma unroll
        for (int j = 0; j < 16; ++j) {         // exp rows R0-16..R0-31
          const float* rp = &ringB[(R0 - 16 - j) & 63][0];
          eBb[j] = __expf(rp[cb]);  eB1[j] = __expf(rp[c1]);
          eB3[j] = __expf(rp[c3]);  eBx[j] = __expf(rp[cnx]);
        }
        SB0;
        // bodies R0..R0-15: full iff min r > MEET and max r < ilen
        if ((R0 - 15 > MEET) && (R0 < ilen)) {
#pragma unroll
          for (int j = 0; j < 16; ++j) { BBODY_U(eAb[j], eA1[j], eA3[j], eAx[j]) }
        } else {
#pragma unroll 1
          for (int j = 0; j < 16; ++j) { BBODY_G(R0 - j, eAb[j], eA1[j], eA3[j], eAx[j]) }
        }
        if (lane < CC) {                       // gload rows R0-48..R0-63
#pragma unroll
          for (int i = 0; i < 16; ++i)
            async_row_load(lg + (size_t)(R0 - 48 - i) * CC + lane,
                           &ringB[(R0 - 48 - i) & 63][0]);
        }
        WAITV(16); SB0;
#pragma unroll
        for (int j = 0; j < 16; ++j) {         // exp rows R0-32..R0-47
          const float* rp = &ringB[(R0 - 32 - j) & 63][0];
          eAb[j] = __expf(rp[cb]);  eA1[j] = __expf(rp[c1]);
          eA3[j] = __expf(rp[c3]);  eAx[j] = __expf(rp[cnx]);
        }
        SB0;
        // bodies R0-16..R0-31
        if ((R0 - 31 > MEET) && (R0 - 16 < ilen)) {
#pragma unroll
          for (int j = 0; j < 16; ++j) { BBODY_U(eBb[j], eB1[j], eB3[j], eBx[j]) }
        } else {
#pragma unroll 1
          for (int j = 0; j < 16; ++j) { BBODY_G(R0 - 16 - j, eBb[j], eB1[j], eB3[j], eBx[j]) }
        }
        {                                      // renorm every 32 bodies
          int h = imax(imax(hi32(b0), hi32(b1)), imax(hi32(b2), hi32(b3)));
          int e = wave_imax(h) >> 20;
          EaccB += e - 1023;
          double s = __longlong_as_double((long long)(2046 - e) << 52);
          b0 *= s; b1 *= s; b2 *= s; b3 *= s; nb0 *= s; nb1 *= s;
        }
      }
#undef BBODY_U
#undef BBODY_G
      asm volatile("s_waitcnt vmcnt(0)");      // drain leftover gloads
      bsh[lane][0] = b0; bsh[lane][1] = b1;
      bsh[lane][2] = b2; bsh[lane][3] = b3;
      if (lane == 0) eaccsh = EaccB;
    }
  }

  __syncthreads();                             // publish beta, S_Z halves

  if (wave == 0) {
    double contrib = fa0 * bsh[lane][0] + fa1 * bsh[lane][1]
                   + fa2 * bsh[lane][2] + fa3 * bsh[lane][3];
#pragma unroll
    for (int o = 32; o; o >>= 1) contrib += __shfl_xor(contrib, o, 64);
    if (lane == 0) {
      long long u = __double_as_longlong(contrib);
      int e = (int)((u >> 52) & 0x7FF) - 1023;
      double mant = __longlong_as_double(
          (u & 0xFFFFFFFFFFFFFULL) | 0x3FF0000000000000ULL);
      double lc = (double)e * LN2 + (double)__logf((float)mant);
      double loss = -(lc + (double)(EaccA + eaccsh) * LN2
                      - (double)(szsh[0] + szsh[1]));
      out[b] = (float)loss;
    }
  }
}

extern "C" void kernel_launch(void* const* d_in, const int* in_sizes, int n_in,
                              void* d_out, int out_size, void* d_ws, size_t ws_size,
                              hipStream_t stream) {
  const float* logits = (const float*)d_in[0];
  const int* labels   = (const int*)d_in[1];
  const int* ilen     = (const int*)d_in[2];
  const int* llen     = (const int*)d_in[3];
  float* out          = (float*)d_out;
  (void)in_sizes; (void)n_in; (void)out_size; (void)d_ws; (void)ws_size;
  hipLaunchKernelGGL(ctc_fused, dim3(BB), dim3(256), 0, stream,
                     logits, labels, ilen, llen, out);
}